// Round 8
// baseline (194.394 us; speedup 1.0000x reference)
//
#include <hip/hip_runtime.h>
#include <math.h>

#define TT 2
#define CH 128
#define HH 96
#define WW 96
#define HWS 9216            // H*W
#define QTOT 18432          // T*H*W
#define QC (QTOT*CH)
#define HD 32
#define KTOP 16
#define SCALE 0.17677669529663687f  // 32^-0.5

#define SEG 16              // queries per attn block (one row segment)
#define PR 8                // patch rows
#define PC 23               // patch cols
#define PSTRIDE 36          // floats per patch pixel in LDS (144 B = 9 x 16 B)

// wbuf (bf16 shorts): wq_hi@0 wq_lo@16384 wk_hi@32768 wk_lo@49152 wv_hi@65536 pj_hi@81920
#define WB_TOT 98304

typedef __attribute__((ext_vector_type(8))) short short8;
typedef __attribute__((ext_vector_type(4))) float floatx4;

__device__ __forceinline__ unsigned short f2bf(float f) {
    union { float f; unsigned u; } x; x.f = f;
    unsigned r = x.u + 0x7fffu + ((x.u >> 16) & 1u);
    return (unsigned short)(r >> 16);
}
__device__ __forceinline__ float bf2f(unsigned short h) {
    return __uint_as_float(((unsigned)h) << 16);
}

__device__ __forceinline__ int refl(int x, int n) {
    x = x < 0 ? -x : x;
    return x >= n ? 2 * (n - 1) - x : x;
}

// ------ FUSED depthwise 3x3 + bf16 convert; block x==288 does pointwise-W prep ---------
__global__ __launch_bounds__(256) void dwcvt_kernel(
    const float* __restrict__ x,
    const float* __restrict__ wq, const float* __restrict__ wk, const float* __restrict__ wv,
    const float* __restrict__ wq_pw, const float* __restrict__ wk_pw,
    const float* __restrict__ wv_pw, const float* __restrict__ proj_w,
    unsigned short* __restrict__ qk_hi,   // [2][p][c]
    unsigned short* __restrict__ qk_lo,   // [2][p][c]
    unsigned short* __restrict__ v_bf,    // [p][c]
    unsigned short* __restrict__ wbuf)
{
    int t = threadIdx.x;
    if (blockIdx.x == 288) {              // one-shot weight conversion
        int y = blockIdx.y;               // 0=wq_pw(hi+lo) 1=wk_pw(hi+lo) 2=wv_pw 3=proj_w
        const float* src = y == 0 ? wq_pw : (y == 1 ? wk_pw : (y == 2 ? wv_pw : proj_w));
        unsigned short* hi = wbuf + (y == 0 ? 0 : (y == 1 ? 32768 : (y == 2 ? 65536 : 81920)));
#pragma unroll
        for (int r = 0; r < 16; r++) {
            int idx = r * 256 + t;        // float4 index, 4096 total = 128x128
            float4 w4 = *(const float4*)(src + idx * 4);
            unsigned short hx = f2bf(w4.x), hy = f2bf(w4.y), hz = f2bf(w4.z), hw = f2bf(w4.w);
            uint2 pk;
            pk.x = hx | ((unsigned)hy << 16); pk.y = hz | ((unsigned)hw << 16);
            *(uint2*)(hi + idx * 4) = pk;
            if (y < 2) {
                unsigned short lx = f2bf(w4.x - bf2f(hx)), ly = f2bf(w4.y - bf2f(hy));
                unsigned short lz = f2bf(w4.z - bf2f(hz)), lw = f2bf(w4.w - bf2f(hw));
                pk.x = lx | ((unsigned)ly << 16); pk.y = lz | ((unsigned)lw << 16);
                *(uint2*)(hi + 16384 + idx * 4) = pk;
            }
        }
        return;
    }

    int pl = t & 63;
    int cg = __builtin_amdgcn_readfirstlane(t >> 6);   // wave-uniform channel group
    int p  = blockIdx.x * 64 + pl;
    int c0 = blockIdx.y * 32 + cg * 8;
    int hw = p % HWS;
    int tt = p / HWS;
    int i = hw / WW, j = hw % WW;

    unsigned qh[4], ql[4], kh[4], kl[4], vh4[4];
#pragma unroll
    for (int ic = 0; ic < 8; ic += 2) {
        float sv[3][2];
#pragma unroll
        for (int u = 0; u < 2; u++) {
            int c = c0 + ic + u;
            const float* xp = x + (size_t)(tt * CH + c) * HWS;
            float w0[9], w1[9], w2[9];
#pragma unroll
            for (int r = 0; r < 9; r++) {
                w0[r] = wq[c * 9 + r]; w1[r] = wk[c * 9 + r]; w2[r] = wv[c * 9 + r];
            }
            float s0 = 0.f, s1 = 0.f, s2 = 0.f;
#pragma unroll
            for (int r = 0; r < 3; r++) {
                int ii = i + r - 1;
                if (ii < 0 || ii >= HH) continue;
#pragma unroll
                for (int ss = 0; ss < 3; ss++) {
                    int jj = j + ss - 1;
                    if (jj < 0 || jj >= WW) continue;
                    float xv = xp[ii * WW + jj];
                    s0 += xv * w0[r * 3 + ss];
                    s1 += xv * w1[r * 3 + ss];
                    s2 += xv * w2[r * 3 + ss];
                }
            }
            sv[0][u] = s0; sv[1][u] = s1; sv[2][u] = s2;
        }
        int w = ic >> 1;
        unsigned short h0 = f2bf(sv[0][0]), h1 = f2bf(sv[0][1]);
        qh[w] = h0 | ((unsigned)h1 << 16);
        ql[w] = f2bf(sv[0][0] - bf2f(h0)) | ((unsigned)f2bf(sv[0][1] - bf2f(h1)) << 16);
        h0 = f2bf(sv[1][0]); h1 = f2bf(sv[1][1]);
        kh[w] = h0 | ((unsigned)h1 << 16);
        kl[w] = f2bf(sv[1][0] - bf2f(h0)) | ((unsigned)f2bf(sv[1][1] - bf2f(h1)) << 16);
        vh4[w] = f2bf(sv[2][0]) | ((unsigned)f2bf(sv[2][1]) << 16);
    }
    size_t off = (size_t)p * CH + c0;
    uint4 pk;
    pk.x = qh[0]; pk.y = qh[1]; pk.z = qh[2]; pk.w = qh[3];
    *(uint4*)(qk_hi + off) = pk;
    pk.x = ql[0]; pk.y = ql[1]; pk.z = ql[2]; pk.w = ql[3];
    *(uint4*)(qk_lo + off) = pk;
    pk.x = kh[0]; pk.y = kh[1]; pk.z = kh[2]; pk.w = kh[3];
    *(uint4*)(qk_hi + (size_t)QC + off) = pk;
    pk.x = kl[0]; pk.y = kl[1]; pk.z = kl[2]; pk.w = kl[3];
    *(uint4*)(qk_lo + (size_t)QC + off) = pk;
    pk.x = vh4[0]; pk.y = vh4[1]; pk.z = vh4[2]; pk.w = vh4[3];
    *(uint4*)(v_bf + off) = pk;
}

// ------ ONE dispatch: y=0/1 qk bf16x3 GEMM -> fp32, y=2 v GEMM -> per-head bf16 --------
// v7: no LDS weight staging; B fragments read directly from L2-resident weights.
__global__ __launch_bounds__(256) void qkv_mfma(
    const unsigned short* __restrict__ Ahi,   // [2][p][c]
    const unsigned short* __restrict__ Alo,
    const unsigned short* __restrict__ Avb,   // v_bf [p][c]
    const unsigned short* __restrict__ wbuf,  // prepped bf16 weights
    const float* __restrict__ bq, const float* __restrict__ bk, const float* __restrict__ bv,
    float* __restrict__ qkf,                  // q -> qkf[0], k -> qkf[1] ([p][c] fp32)
    unsigned short* __restrict__ vh)          // [4][QTOT][32] bf16
{
    int sel = blockIdx.y;
    int t = threadIdx.x;
    int wv = t >> 6, lane = t & 63;
    int m = lane & 15, quad = lane >> 4;
    int p0 = blockIdx.x * 64;
    int o0 = wv * 32;

    if (sel == 2) {                    // v GEMM -> per-head table
        const unsigned short* Wg = wbuf + 65536;
        float bb[2];
#pragma unroll
        for (int ot = 0; ot < 2; ot++) bb[ot] = bv[o0 + ot * 16 + m];
        floatx4 acc[4][2];
#pragma unroll
        for (int i = 0; i < 4; i++)
#pragma unroll
            for (int j = 0; j < 2; j++) acc[i][j] = (floatx4){0.f, 0.f, 0.f, 0.f};
#pragma unroll
        for (int kc = 0; kc < 4; kc++) {
            short8 a[4], b[2];
#pragma unroll
            for (int pt = 0; pt < 4; pt++)
                a[pt] = *(const short8*)(Avb + (size_t)(p0 + pt * 16 + m) * CH + kc * 32 + quad * 8);
#pragma unroll
            for (int ot = 0; ot < 2; ot++)
                b[ot] = *(const short8*)(Wg + (size_t)(o0 + ot * 16 + m) * CH + kc * 32 + quad * 8);
#pragma unroll
            for (int pt = 0; pt < 4; pt++)
#pragma unroll
                for (int ot = 0; ot < 2; ot++)
                    acc[pt][ot] = __builtin_amdgcn_mfma_f32_16x16x32_bf16(a[pt], b[ot], acc[pt][ot], 0, 0, 0);
        }
        unsigned short* vhh = vh + (size_t)wv * QTOT * 32;   // head = wv
#pragma unroll
        for (int pt = 0; pt < 4; pt++)
#pragma unroll
            for (int ot = 0; ot < 2; ot++)
#pragma unroll
                for (int reg = 0; reg < 4; reg++) {
                    int p = p0 + pt * 16 + quad * 4 + reg;
                    vhh[(size_t)p * 32 + ot * 16 + m] = f2bf(acc[pt][ot][reg] + bb[ot]);
                }
        return;
    }

    // sel 0/1: q,k via bf16x3 split (fp32-emulating)
    const unsigned short* Wh_g = wbuf + sel * 32768;
    const unsigned short* Wl_g = Wh_g + 16384;
    const float* bias = sel ? bk : bq;
    float scale = sel ? 1.f : SCALE;
    const unsigned short* ah = Ahi + (size_t)sel * QC;
    const unsigned short* al = Alo + (size_t)sel * QC;
    float* O = qkf + (size_t)sel * QC;

    float bb[2];
#pragma unroll
    for (int ot = 0; ot < 2; ot++) bb[ot] = bias[o0 + ot * 16 + m];
    floatx4 acc[4][2];
#pragma unroll
    for (int i = 0; i < 4; i++)
#pragma unroll
        for (int j = 0; j < 2; j++) acc[i][j] = (floatx4){0.f, 0.f, 0.f, 0.f};
#pragma unroll
    for (int kc = 0; kc < 4; kc++) {
        short8 avh[4], avl[4], bh[2], bl[2];
#pragma unroll
        for (int pt = 0; pt < 4; pt++) {
            size_t base = (size_t)(p0 + pt * 16 + m) * CH + kc * 32 + quad * 8;
            avh[pt] = *(const short8*)(ah + base);
            avl[pt] = *(const short8*)(al + base);
        }
#pragma unroll
        for (int ot = 0; ot < 2; ot++) {
            size_t widx = (size_t)(o0 + ot * 16 + m) * CH + kc * 32 + quad * 8;
            bh[ot] = *(const short8*)(Wh_g + widx);
            bl[ot] = *(const short8*)(Wl_g + widx);
        }
#pragma unroll
        for (int pt = 0; pt < 4; pt++)
#pragma unroll
            for (int ot = 0; ot < 2; ot++) {
                acc[pt][ot] = __builtin_amdgcn_mfma_f32_16x16x32_bf16(avh[pt], bh[ot], acc[pt][ot], 0, 0, 0);
                acc[pt][ot] = __builtin_amdgcn_mfma_f32_16x16x32_bf16(avh[pt], bl[ot], acc[pt][ot], 0, 0, 0);
                acc[pt][ot] = __builtin_amdgcn_mfma_f32_16x16x32_bf16(avl[pt], bh[ot], acc[pt][ot], 0, 0, 0);
            }
    }
#pragma unroll
    for (int pt = 0; pt < 4; pt++)
#pragma unroll
        for (int ot = 0; ot < 2; ot++)
#pragma unroll
            for (int reg = 0; reg < 4; reg++) {
                int p = p0 + pt * 16 + quad * 4 + reg;
                O[(size_t)p * CH + o0 + ot * 16 + m] = (acc[pt][ot][reg] + bb[ot]) * scale;
            }
}

// ------ attention v8 = v7 with the ballot threshold search replaced by a 21-stage
//        64-lane bitonic sort (pure VALU/shfl, ZERO serial SALU chain).
//        iskey = ~((key<<6)|(lane^63)) -- all values DISTINCT (lane bits embedded);
//        ascending iskey == key desc, lane asc. After sort, lane 15 holds the
//        16th-largest; selb = (my iskey <= that) reproduces EXACTLY the reference
//        top-16 set. Downstream (selm ballot, mbcnt rank, slot order = lane-asc
//        among selected, summation order) is byte-identical to v7, so absmax must
//        stay exactly 2.441406e-4 (built-in correctness tripwire).
//        Rationale: r5 proved attn time invariant to occupancy (SALU = 1/CU shared
//        by 4 SIMDs is the serialized resource); r6 proved time tracks ballot-chain
//        length. This moves the select entirely onto the 4x-wider VALU.
__global__ __launch_bounds__(1024) void attn_kernel(
    const float* __restrict__ q,    // qkf[0] [p][128] fp32
    const float* __restrict__ k,    // qkf[1]
    const unsigned short* __restrict__ vh,   // [4][QTOT][32] bf16
    unsigned short* __restrict__ att)        // [p][128] bf16
{
    __shared__ float kp[PR * PC * PSTRIDE];   // 25.9 KB
    __shared__ uint2 slot[16][KTOP];          // per-wave compaction, 2 KB
    int h = blockIdx.y;
    int n = blockIdx.x;
    int seg = (n & 7) * 144 + (n >> 3);       // XCD-band swizzle
    int qj0 = (seg % (WW / SEG)) * SEG;
    int qi = (seg / (WW / SEG)) % HH;
    int tt = seg / ((WW / SEG) * HH);
    int t = threadIdx.x;

    // stage reflected k patch: coalesced, linear layout
#pragma unroll
    for (int r = 0; r < 2; r++) {
        int f = r * 1024 + t;
        if (f < PR * PC * 8) {
            int pix = f >> 3, d4 = f & 7;
            int ci = pix / PC, cj = pix - ci * PC;
            int gi = refl(qi + ci - 4, HH);
            int gj = refl(qj0 + cj - 4, WW);
            int gp = tt * HWS + gi * WW + gj;
            *(float4*)(&kp[pix * PSTRIDE + d4 * 4]) =
                *(const float4*)(k + (size_t)gp * CH + h * HD + d4 * 4);
        }
    }

    int wv = t >> 6, lane = t & 63;
    int wvu = __builtin_amdgcn_readfirstlane(wv);   // wave-uniform wave id = query id
    // defensive zero-init: an unwritten slot contributes 0 and gathers pixel 0
    if (lane < KTOP) slot[wvu][lane] = make_uint2(0u, 0u);
    __syncthreads();

    int ci = lane >> 3, cjo = lane & 7;
    int di = ci - 4, dj = cjo - 4;
    int rowoff = tt * HWS + refl(qi + di, HH) * WW;
    const unsigned short* vhh = vh + (size_t)h * QTOT * 32;

    int ql = wvu;                    // this wave's query within the segment
    int qj = qj0 + ql;
    int p = tt * HWS + qi * WW + qj;

    // ---- dist: fp32 dot (q row address is scalar -> s_load broadcast)
    const float* qp = q + (size_t)p * CH + h * HD;
    int pixq = ci * PC + ql + cjo;
    const float* kr = &kp[pixq * PSTRIDE];
    float dist = 0.f;
#pragma unroll
    for (int dd = 0; dd < 8; dd++) {
        float4 qv = *(const float4*)(qp + dd * 4);
        float4 kv = *(const float4*)(kr + dd * 4);
        dist += qv.x * kv.x + qv.y * kv.y + qv.z * kv.z + qv.w * kv.w;
    }

    // ---- order-preserving key; exp hoisted off the select critical path
    unsigned u = __float_as_uint(dist);
    unsigned key = (u & 0x80000000u) ? ~u : (u | 0x80000000u);
    // softmax without shift: dists are O(1e-3), exp is exact-safe
    float e = __expf(dist);

    // composite, all-distinct, inverted so ASCENDING sort = key desc, lane asc
    unsigned long long iskey =
        ~(((unsigned long long)key << 6) | (unsigned long long)(lane ^ 63));

    // ---- 64-lane ascending bitonic sort (21 compare-exchange stages, VALU only)
    unsigned long long v = iskey;
#pragma unroll
    for (int kk = 2; kk <= 64; kk <<= 1) {
#pragma unroll
        for (int j = kk >> 1; j > 0; j >>= 1) {
            unsigned long long o = __shfl_xor(v, j, 64);
            bool takeMin = ((lane & j) == 0) == ((lane & kk) == 0);
            bool less = v < o;
            v = (less == takeMin) ? v : o;
        }
    }
    // lane 15 now holds the 16th-smallest iskey = 16th-largest key (wave-uniform bcast)
    unsigned long long kth = __shfl(v, 15, 64);
    bool selb = (iskey <= kth);                // exactly KTOP lanes (all iskey distinct)
    unsigned long long selm = __ballot(selb);

    int rksel = __builtin_amdgcn_mbcnt_hi(
        (unsigned)(selm >> 32), __builtin_amdgcn_mbcnt_lo((unsigned)selm, 0));
    int cpix = rowoff + refl(qj + dj, WW);
    if (selb && rksel < KTOP)
        slot[wvu][rksel] = make_uint2(__float_as_uint(e), (unsigned)(cpix << 5));

    // ---- weighted v gather, halves split across lanes (0-31: slots 0-7,
    // 32-63: slots 8-15), combined with one xor-32 shuffle per sum
    const int d = lane & (HD - 1);
    const int half8 = (lane >> 5) * 8;
    float acc = 0.f, denom = 0.f;
#pragma unroll
    for (int r = 0; r < 8; r++) {
        uint2 sp = slot[wvu][half8 + r];
        float a0 = __uint_as_float(sp.x);
        denom += a0;
        acc += a0 * bf2f(vhh[(size_t)sp.y + d]);
    }
    acc += __shfl_xor(acc, 32);
    denom += __shfl_xor(denom, 32);
    if (lane < HD)
        att[(size_t)p * CH + h * HD + lane] =
            f2bf(acc * __builtin_amdgcn_rcpf(denom));
}

// ------ proj via bf16 MFMA, v7: no LDS staging (weights direct from L2) -------------
__global__ __launch_bounds__(256) void proj_mfma(
    const unsigned short* __restrict__ A,   // att_bf [p][c] bf16
    const unsigned short* __restrict__ wbuf,
    const float* __restrict__ bias,
    float* __restrict__ out)                // NCHW fp32
{
    const unsigned short* Wg = wbuf + 81920;
    int t = threadIdx.x;
    int wv = t >> 6, lane = t & 63;
    int m = lane & 15, quad = lane >> 4;
    int p0 = blockIdx.x * 64;
    int o0 = wv * 32;
    float bb[2][4];
#pragma unroll
    for (int ot = 0; ot < 2; ot++)
#pragma unroll
        for (int reg = 0; reg < 4; reg++) bb[ot][reg] = bias[o0 + ot * 16 + quad * 4 + reg];
    floatx4 acc[2][4];
#pragma unroll
    for (int i = 0; i < 2; i++)
#pragma unroll
        for (int j = 0; j < 4; j++) acc[i][j] = (floatx4){0.f, 0.f, 0.f, 0.f};
#pragma unroll
    for (int kc = 0; kc < 4; kc++) {
        short8 a[2], b[4];
#pragma unroll
        for (int ot = 0; ot < 2; ot++)
            a[ot] = *(const short8*)(Wg + (size_t)(o0 + ot * 16 + m) * CH + kc * 32 + quad * 8);
#pragma unroll
        for (int pt = 0; pt < 4; pt++)
            b[pt] = *(const short8*)(A + (size_t)(p0 + pt * 16 + m) * CH + kc * 32 + quad * 8);
#pragma unroll
        for (int ot = 0; ot < 2; ot++)
#pragma unroll
            for (int pt = 0; pt < 4; pt++)
                acc[ot][pt] = __builtin_amdgcn_mfma_f32_16x16x32_bf16(a[ot], b[pt], acc[ot][pt], 0, 0, 0);
    }
    int tt = p0 / HWS;
    int hwb = p0 - tt * HWS;
#pragma unroll
    for (int ot = 0; ot < 2; ot++)
#pragma unroll
        for (int pt = 0; pt < 4; pt++)
#pragma unroll
            for (int reg = 0; reg < 4; reg++) {
                int o = o0 + ot * 16 + quad * 4 + reg;
                int hw = hwb + pt * 16 + m;
                out[((size_t)(tt * CH + o)) * HWS + hw] = acc[ot][pt][reg] + bb[ot][reg];
            }
}

extern "C" void kernel_launch(void* const* d_in, const int* in_sizes, int n_in,
                              void* d_out, int out_size, void* d_ws, size_t ws_size,
                              hipStream_t stream) {
    const float* vid    = (const float*)d_in[0];
    const float* wq_dw  = (const float*)d_in[1];
    const float* wq_pw  = (const float*)d_in[2];
    const float* bq     = (const float*)d_in[3];
    const float* wk_dw  = (const float*)d_in[4];
    const float* wk_pw  = (const float*)d_in[5];
    const float* bk     = (const float*)d_in[6];
    const float* wv_dw  = (const float*)d_in[7];
    const float* wv_pw  = (const float*)d_in[8];
    const float* bv     = (const float*)d_in[9];
    const float* proj_w = (const float*)d_in[10];
    const float* proj_b = (const float*)d_in[11];
    float* out = (float*)d_out;

    // workspace (~47.3 MB):
    //   qkf   : 2*QC fp32 [p][c]
    //   vh    : QC bf16 [4][QTOT][32]
    //   qk_hi : 2*QC bf16, qk_lo : 2*QC bf16
    //   v_bf  : QC bf16 (aliased as att_bf after qkv_mfma consumes it)
    //   wbuf  : WB_TOT bf16 prepped pointwise/proj weights
    float* qkf = (float*)d_ws;
    unsigned short* vh = (unsigned short*)(qkf + (size_t)2 * QC);
    unsigned short* qk_hi = vh + (size_t)QC;
    unsigned short* qk_lo = qk_hi + (size_t)2 * QC;
    unsigned short* v_bf = qk_lo + (size_t)2 * QC;
    unsigned short* wbuf = v_bf + (size_t)QC;
    unsigned short* att_bf = v_bf;

    dwcvt_kernel<<<dim3(289, 4), 256, 0, stream>>>(
        vid, wq_dw, wk_dw, wv_dw, wq_pw, wk_pw, wv_pw, proj_w,
        qk_hi, qk_lo, v_bf, wbuf);
    qkv_mfma<<<dim3(QTOT / 64, 3), 256, 0, stream>>>(
        qk_hi, qk_lo, v_bf, wbuf, bq, bk, bv, qkf, vh);
    attn_kernel<<<dim3(TT * HH * (WW / SEG), 4), 1024, 0, stream>>>(
        qkf, qkf + (size_t)QC, vh, att_bf);
    proj_mfma<<<QTOT / 64, 256, 0, stream>>>(att_bf, wbuf, proj_b, out);
}

// Round 9
// 180.397 us; speedup vs baseline: 1.0776x; 1.0776x over previous
//
#include <hip/hip_runtime.h>
#include <math.h>

#define TT 2
#define CH 128
#define HH 96
#define WW 96
#define HWS 9216            // H*W
#define QTOT 18432          // T*H*W
#define QC (QTOT*CH)
#define HD 32
#define KTOP 16
#define SCALE 0.17677669529663687f  // 32^-0.5

#define SEG 16              // queries per attn block (one row segment)
#define PR 8                // patch rows
#define PC 23               // patch cols
#define PSTRIDE 36          // floats per patch pixel in LDS (144 B = 9 x 16 B)

// wbuf (bf16 shorts): wq_hi@0 wq_lo@16384 wk_hi@32768 wk_lo@49152 wv_hi@65536 pj_hi@81920
#define WB_TOT 98304

typedef __attribute__((ext_vector_type(8))) short short8;
typedef __attribute__((ext_vector_type(4))) float floatx4;

__device__ __forceinline__ unsigned short f2bf(float f) {
    union { float f; unsigned u; } x; x.f = f;
    unsigned r = x.u + 0x7fffu + ((x.u >> 16) & 1u);
    return (unsigned short)(r >> 16);
}
__device__ __forceinline__ float bf2f(unsigned short h) {
    return __uint_as_float(((unsigned)h) << 16);
}

__device__ __forceinline__ int refl(int x, int n) {
    x = x < 0 ? -x : x;
    return x >= n ? 2 * (n - 1) - x : x;
}

// ------ FUSED depthwise 3x3 + bf16 convert; block x==288 does pointwise-W prep ---------
__global__ __launch_bounds__(256) void dwcvt_kernel(
    const float* __restrict__ x,
    const float* __restrict__ wq, const float* __restrict__ wk, const float* __restrict__ wv,
    const float* __restrict__ wq_pw, const float* __restrict__ wk_pw,
    const float* __restrict__ wv_pw, const float* __restrict__ proj_w,
    unsigned short* __restrict__ qk_hi,   // [2][p][c]
    unsigned short* __restrict__ qk_lo,   // [2][p][c]
    unsigned short* __restrict__ v_bf,    // [p][c]
    unsigned short* __restrict__ wbuf)
{
    int t = threadIdx.x;
    if (blockIdx.x == 288) {              // one-shot weight conversion
        int y = blockIdx.y;               // 0=wq_pw(hi+lo) 1=wk_pw(hi+lo) 2=wv_pw 3=proj_w
        const float* src = y == 0 ? wq_pw : (y == 1 ? wk_pw : (y == 2 ? wv_pw : proj_w));
        unsigned short* hi = wbuf + (y == 0 ? 0 : (y == 1 ? 32768 : (y == 2 ? 65536 : 81920)));
#pragma unroll
        for (int r = 0; r < 16; r++) {
            int idx = r * 256 + t;        // float4 index, 4096 total = 128x128
            float4 w4 = *(const float4*)(src + idx * 4);
            unsigned short hx = f2bf(w4.x), hy = f2bf(w4.y), hz = f2bf(w4.z), hw = f2bf(w4.w);
            uint2 pk;
            pk.x = hx | ((unsigned)hy << 16); pk.y = hz | ((unsigned)hw << 16);
            *(uint2*)(hi + idx * 4) = pk;
            if (y < 2) {
                unsigned short lx = f2bf(w4.x - bf2f(hx)), ly = f2bf(w4.y - bf2f(hy));
                unsigned short lz = f2bf(w4.z - bf2f(hz)), lw = f2bf(w4.w - bf2f(hw));
                pk.x = lx | ((unsigned)ly << 16); pk.y = lz | ((unsigned)lw << 16);
                *(uint2*)(hi + 16384 + idx * 4) = pk;
            }
        }
        return;
    }

    int pl = t & 63;
    int cg = __builtin_amdgcn_readfirstlane(t >> 6);   // wave-uniform channel group
    int p  = blockIdx.x * 64 + pl;
    int c0 = blockIdx.y * 32 + cg * 8;
    int hw = p % HWS;
    int tt = p / HWS;
    int i = hw / WW, j = hw % WW;

    unsigned qh[4], ql[4], kh[4], kl[4], vh4[4];
#pragma unroll
    for (int ic = 0; ic < 8; ic += 2) {
        float sv[3][2];
#pragma unroll
        for (int u = 0; u < 2; u++) {
            int c = c0 + ic + u;
            const float* xp = x + (size_t)(tt * CH + c) * HWS;
            float w0[9], w1[9], w2[9];
#pragma unroll
            for (int r = 0; r < 9; r++) {
                w0[r] = wq[c * 9 + r]; w1[r] = wk[c * 9 + r]; w2[r] = wv[c * 9 + r];
            }
            float s0 = 0.f, s1 = 0.f, s2 = 0.f;
#pragma unroll
            for (int r = 0; r < 3; r++) {
                int ii = i + r - 1;
                if (ii < 0 || ii >= HH) continue;
#pragma unroll
                for (int ss = 0; ss < 3; ss++) {
                    int jj = j + ss - 1;
                    if (jj < 0 || jj >= WW) continue;
                    float xv = xp[ii * WW + jj];
                    s0 += xv * w0[r * 3 + ss];
                    s1 += xv * w1[r * 3 + ss];
                    s2 += xv * w2[r * 3 + ss];
                }
            }
            sv[0][u] = s0; sv[1][u] = s1; sv[2][u] = s2;
        }
        int w = ic >> 1;
        unsigned short h0 = f2bf(sv[0][0]), h1 = f2bf(sv[0][1]);
        qh[w] = h0 | ((unsigned)h1 << 16);
        ql[w] = f2bf(sv[0][0] - bf2f(h0)) | ((unsigned)f2bf(sv[0][1] - bf2f(h1)) << 16);
        h0 = f2bf(sv[1][0]); h1 = f2bf(sv[1][1]);
        kh[w] = h0 | ((unsigned)h1 << 16);
        kl[w] = f2bf(sv[1][0] - bf2f(h0)) | ((unsigned)f2bf(sv[1][1] - bf2f(h1)) << 16);
        vh4[w] = f2bf(sv[2][0]) | ((unsigned)f2bf(sv[2][1]) << 16);
    }
    size_t off = (size_t)p * CH + c0;
    uint4 pk;
    pk.x = qh[0]; pk.y = qh[1]; pk.z = qh[2]; pk.w = qh[3];
    *(uint4*)(qk_hi + off) = pk;
    pk.x = ql[0]; pk.y = ql[1]; pk.z = ql[2]; pk.w = ql[3];
    *(uint4*)(qk_lo + off) = pk;
    pk.x = kh[0]; pk.y = kh[1]; pk.z = kh[2]; pk.w = kh[3];
    *(uint4*)(qk_hi + (size_t)QC + off) = pk;
    pk.x = kl[0]; pk.y = kl[1]; pk.z = kl[2]; pk.w = kl[3];
    *(uint4*)(qk_lo + (size_t)QC + off) = pk;
    pk.x = vh4[0]; pk.y = vh4[1]; pk.z = vh4[2]; pk.w = vh4[3];
    *(uint4*)(v_bf + off) = pk;
}

// ------ ONE dispatch: y=0/1 qk bf16x3 GEMM -> fp32, y=2 v GEMM -> per-head bf16 --------
// v7: no LDS weight staging; B fragments read directly from L2-resident weights.
__global__ __launch_bounds__(256) void qkv_mfma(
    const unsigned short* __restrict__ Ahi,   // [2][p][c]
    const unsigned short* __restrict__ Alo,
    const unsigned short* __restrict__ Avb,   // v_bf [p][c]
    const unsigned short* __restrict__ wbuf,  // prepped bf16 weights
    const float* __restrict__ bq, const float* __restrict__ bk, const float* __restrict__ bv,
    float* __restrict__ qkf,                  // q -> qkf[0], k -> qkf[1] ([p][c] fp32)
    unsigned short* __restrict__ vh)          // [4][QTOT][32] bf16
{
    int sel = blockIdx.y;
    int t = threadIdx.x;
    int wv = t >> 6, lane = t & 63;
    int m = lane & 15, quad = lane >> 4;
    int p0 = blockIdx.x * 64;
    int o0 = wv * 32;

    if (sel == 2) {                    // v GEMM -> per-head table
        const unsigned short* Wg = wbuf + 65536;
        float bb[2];
#pragma unroll
        for (int ot = 0; ot < 2; ot++) bb[ot] = bv[o0 + ot * 16 + m];
        floatx4 acc[4][2];
#pragma unroll
        for (int i = 0; i < 4; i++)
#pragma unroll
            for (int j = 0; j < 2; j++) acc[i][j] = (floatx4){0.f, 0.f, 0.f, 0.f};
#pragma unroll
        for (int kc = 0; kc < 4; kc++) {
            short8 a[4], b[2];
#pragma unroll
            for (int pt = 0; pt < 4; pt++)
                a[pt] = *(const short8*)(Avb + (size_t)(p0 + pt * 16 + m) * CH + kc * 32 + quad * 8);
#pragma unroll
            for (int ot = 0; ot < 2; ot++)
                b[ot] = *(const short8*)(Wg + (size_t)(o0 + ot * 16 + m) * CH + kc * 32 + quad * 8);
#pragma unroll
            for (int pt = 0; pt < 4; pt++)
#pragma unroll
                for (int ot = 0; ot < 2; ot++)
                    acc[pt][ot] = __builtin_amdgcn_mfma_f32_16x16x32_bf16(a[pt], b[ot], acc[pt][ot], 0, 0, 0);
        }
        unsigned short* vhh = vh + (size_t)wv * QTOT * 32;   // head = wv
#pragma unroll
        for (int pt = 0; pt < 4; pt++)
#pragma unroll
            for (int ot = 0; ot < 2; ot++)
#pragma unroll
                for (int reg = 0; reg < 4; reg++) {
                    int p = p0 + pt * 16 + quad * 4 + reg;
                    vhh[(size_t)p * 32 + ot * 16 + m] = f2bf(acc[pt][ot][reg] + bb[ot]);
                }
        return;
    }

    // sel 0/1: q,k via bf16x3 split (fp32-emulating)
    const unsigned short* Wh_g = wbuf + sel * 32768;
    const unsigned short* Wl_g = Wh_g + 16384;
    const float* bias = sel ? bk : bq;
    float scale = sel ? 1.f : SCALE;
    const unsigned short* ah = Ahi + (size_t)sel * QC;
    const unsigned short* al = Alo + (size_t)sel * QC;
    float* O = qkf + (size_t)sel * QC;

    float bb[2];
#pragma unroll
    for (int ot = 0; ot < 2; ot++) bb[ot] = bias[o0 + ot * 16 + m];
    floatx4 acc[4][2];
#pragma unroll
    for (int i = 0; i < 4; i++)
#pragma unroll
        for (int j = 0; j < 2; j++) acc[i][j] = (floatx4){0.f, 0.f, 0.f, 0.f};
#pragma unroll
    for (int kc = 0; kc < 4; kc++) {
        short8 avh[4], avl[4], bh[2], bl[2];
#pragma unroll
        for (int pt = 0; pt < 4; pt++) {
            size_t base = (size_t)(p0 + pt * 16 + m) * CH + kc * 32 + quad * 8;
            avh[pt] = *(const short8*)(ah + base);
            avl[pt] = *(const short8*)(al + base);
        }
#pragma unroll
        for (int ot = 0; ot < 2; ot++) {
            size_t widx = (size_t)(o0 + ot * 16 + m) * CH + kc * 32 + quad * 8;
            bh[ot] = *(const short8*)(Wh_g + widx);
            bl[ot] = *(const short8*)(Wl_g + widx);
        }
#pragma unroll
        for (int pt = 0; pt < 4; pt++)
#pragma unroll
            for (int ot = 0; ot < 2; ot++) {
                acc[pt][ot] = __builtin_amdgcn_mfma_f32_16x16x32_bf16(avh[pt], bh[ot], acc[pt][ot], 0, 0, 0);
                acc[pt][ot] = __builtin_amdgcn_mfma_f32_16x16x32_bf16(avh[pt], bl[ot], acc[pt][ot], 0, 0, 0);
                acc[pt][ot] = __builtin_amdgcn_mfma_f32_16x16x32_bf16(avl[pt], bh[ot], acc[pt][ot], 0, 0, 0);
            }
    }
#pragma unroll
    for (int pt = 0; pt < 4; pt++)
#pragma unroll
        for (int ot = 0; ot < 2; ot++)
#pragma unroll
            for (int reg = 0; reg < 4; reg++) {
                int p = p0 + pt * 16 + quad * 4 + reg;
                O[(size_t)p * CH + o0 + ot * 16 + m] = (acc[pt][ot][reg] + bb[ot]) * scale;
            }
}

// ------ attention v9 = restore v7 (best-known): two-level ballot select.
//        r8 lesson: 64-bit shfl = 2x ds_bpermute (LDS crossbar) -- a 21-stage
//        bitonic sort tripled LDS pressure and cost +16us. The select lever is
//        now bracketed: 32-ballot (49us) > 16-ballot two-level (44us) < sort (60us).
__global__ __launch_bounds__(1024) void attn_kernel(
    const float* __restrict__ q,    // qkf[0] [p][128] fp32
    const float* __restrict__ k,    // qkf[1]
    const unsigned short* __restrict__ vh,   // [4][QTOT][32] bf16
    unsigned short* __restrict__ att)        // [p][128] bf16
{
    __shared__ float kp[PR * PC * PSTRIDE];   // 25.9 KB
    __shared__ uint2 slot[16][KTOP];          // per-wave compaction, 2 KB
    int h = blockIdx.y;
    int n = blockIdx.x;
    int seg = (n & 7) * 144 + (n >> 3);       // XCD-band swizzle
    int qj0 = (seg % (WW / SEG)) * SEG;
    int qi = (seg / (WW / SEG)) % HH;
    int tt = seg / ((WW / SEG) * HH);
    int t = threadIdx.x;

    // stage reflected k patch: coalesced, linear layout
#pragma unroll
    for (int r = 0; r < 2; r++) {
        int f = r * 1024 + t;
        if (f < PR * PC * 8) {
            int pix = f >> 3, d4 = f & 7;
            int ci = pix / PC, cj = pix - ci * PC;
            int gi = refl(qi + ci - 4, HH);
            int gj = refl(qj0 + cj - 4, WW);
            int gp = tt * HWS + gi * WW + gj;
            *(float4*)(&kp[pix * PSTRIDE + d4 * 4]) =
                *(const float4*)(k + (size_t)gp * CH + h * HD + d4 * 4);
        }
    }

    int wv = t >> 6, lane = t & 63;
    int wvu = __builtin_amdgcn_readfirstlane(wv);   // wave-uniform wave id = query id
    // defensive zero-init: an unwritten slot contributes 0 and gathers pixel 0
    if (lane < KTOP) slot[wvu][lane] = make_uint2(0u, 0u);
    __syncthreads();

    int ci = lane >> 3, cjo = lane & 7;
    int di = ci - 4, dj = cjo - 4;
    int rowoff = tt * HWS + refl(qi + di, HH) * WW;
    const unsigned long long below = (1ull << lane) - 1ull;
    const unsigned short* vhh = vh + (size_t)h * QTOT * 32;

    int ql = wvu;                    // this wave's query within the segment
    int qj = qj0 + ql;
    int p = tt * HWS + qi * WW + qj;

    // ---- dist: fp32 dot (q row address is scalar -> s_load broadcast)
    const float* qp = q + (size_t)p * CH + h * HD;
    int pixq = ci * PC + ql + cjo;
    const float* kr = &kp[pixq * PSTRIDE];
    float dist = 0.f;
#pragma unroll
    for (int dd = 0; dd < 8; dd++) {
        float4 qv = *(const float4*)(qp + dd * 4);
        float4 kv = *(const float4*)(kr + dd * 4);
        dist += qv.x * kv.x + qv.y * kv.y + qv.z * kv.z + qv.w * kv.w;
    }

    // ---- order-preserving key; exp hoisted out of the select dependency
    unsigned u = __float_as_uint(dist);
    unsigned key = (u & 0x80000000u) ? ~u : (u | 0x80000000u);
    unsigned khi = key >> 16, klo = key & 0xffffu;
    // softmax without shift: dists are O(1e-3), exp is exact-safe
    float e = __expf(dist);

    // ---- level 1: 16-ballot threshold search on the high 16 bits.
    unsigned Lh = 0u;
#pragma unroll
    for (int bit = 15; bit >= 0; --bit) {
        unsigned C = Lh | (1u << bit);
        unsigned long long b = __ballot(khi >= C);
        Lh = (__popcll(b) >= KTOP) ? C : Lh;
    }
    bool gth = khi > Lh;
    bool eqh = (khi == Lh);
    unsigned long long gtmh = __ballot(gth);
    unsigned long long eqmh = __ballot(eqh);
    int need = KTOP - __popcll(gtmh);          // >= 1; class size >= need
    bool selb;
    unsigned long long selm;
    if (__popcll(eqmh) == need) {
        // fast path (wave-uniform): class exactly fills -> all of it selected.
        selb = gth || eqh;
        selm = gtmh | eqmh;
    } else {
        // refine: need-th largest klo within the hi-eq class
        unsigned Ll = 0u;
#pragma unroll
        for (int bit = 15; bit >= 0; --bit) {
            unsigned C = Ll | (1u << bit);
            unsigned long long b = __ballot(klo >= C) & eqmh;
            Ll = (__popcll(b) >= need) ? C : Ll;
        }
        unsigned long long gtml = __ballot(klo > Ll) & eqmh;
        unsigned long long eqml = __ballot(klo == Ll) & eqmh;
        int needl = need - __popcll(gtml);     // >= 1
        int rk = __popcll(eqml & below);
        bool gtl = eqh && (klo > Ll);
        bool eql = eqh && (klo == Ll);
        selb = gth || gtl || (eql && rk < needl);
        selm = __ballot(selb);
    }
    int rksel = __builtin_amdgcn_mbcnt_hi(
        (unsigned)(selm >> 32), __builtin_amdgcn_mbcnt_lo((unsigned)selm, 0));
    int cpix = rowoff + refl(qj + dj, WW);
    if (selb && rksel < KTOP)
        slot[wvu][rksel] = make_uint2(__float_as_uint(e), (unsigned)(cpix << 5));

    // ---- weighted v gather, halves split across lanes (0-31: slots 0-7,
    // 32-63: slots 8-15), combined with one xor-32 shuffle per sum
    const int d = lane & (HD - 1);
    const int half8 = (lane >> 5) * 8;
    float acc = 0.f, denom = 0.f;
#pragma unroll
    for (int r = 0; r < 8; r++) {
        uint2 sp = slot[wvu][half8 + r];
        float a0 = __uint_as_float(sp.x);
        denom += a0;
        acc += a0 * bf2f(vhh[(size_t)sp.y + d]);
    }
    acc += __shfl_xor(acc, 32);
    denom += __shfl_xor(denom, 32);
    if (lane < HD)
        att[(size_t)p * CH + h * HD + lane] =
            f2bf(acc * __builtin_amdgcn_rcpf(denom));
}

// ------ proj via bf16 MFMA, v7: no LDS staging (weights direct from L2) -------------
__global__ __launch_bounds__(256) void proj_mfma(
    const unsigned short* __restrict__ A,   // att_bf [p][c] bf16
    const unsigned short* __restrict__ wbuf,
    const float* __restrict__ bias,
    float* __restrict__ out)                // NCHW fp32
{
    const unsigned short* Wg = wbuf + 81920;
    int t = threadIdx.x;
    int wv = t >> 6, lane = t & 63;
    int m = lane & 15, quad = lane >> 4;
    int p0 = blockIdx.x * 64;
    int o0 = wv * 32;
    float bb[2][4];
#pragma unroll
    for (int ot = 0; ot < 2; ot++)
#pragma unroll
        for (int reg = 0; reg < 4; reg++) bb[ot][reg] = bias[o0 + ot * 16 + quad * 4 + reg];
    floatx4 acc[2][4];
#pragma unroll
    for (int i = 0; i < 2; i++)
#pragma unroll
        for (int j = 0; j < 4; j++) acc[i][j] = (floatx4){0.f, 0.f, 0.f, 0.f};
#pragma unroll
    for (int kc = 0; kc < 4; kc++) {
        short8 a[2], b[4];
#pragma unroll
        for (int ot = 0; ot < 2; ot++)
            a[ot] = *(const short8*)(Wg + (size_t)(o0 + ot * 16 + m) * CH + kc * 32 + quad * 8);
#pragma unroll
        for (int pt = 0; pt < 4; pt++)
            b[pt] = *(const short8*)(A + (size_t)(p0 + pt * 16 + m) * CH + kc * 32 + quad * 8);
#pragma unroll
        for (int ot = 0; ot < 2; ot++)
#pragma unroll
            for (int pt = 0; pt < 4; pt++)
                acc[ot][pt] = __builtin_amdgcn_mfma_f32_16x16x32_bf16(a[ot], b[pt], acc[ot][pt], 0, 0, 0);
    }
    int tt = p0 / HWS;
    int hwb = p0 - tt * HWS;
#pragma unroll
    for (int ot = 0; ot < 2; ot++)
#pragma unroll
        for (int pt = 0; pt < 4; pt++)
#pragma unroll
            for (int reg = 0; reg < 4; reg++) {
                int o = o0 + ot * 16 + quad * 4 + reg;
                int hw = hwb + pt * 16 + m;
                out[((size_t)(tt * CH + o)) * HWS + hw] = acc[ot][pt][reg] + bb[ot][reg];
            }
}

extern "C" void kernel_launch(void* const* d_in, const int* in_sizes, int n_in,
                              void* d_out, int out_size, void* d_ws, size_t ws_size,
                              hipStream_t stream) {
    const float* vid    = (const float*)d_in[0];
    const float* wq_dw  = (const float*)d_in[1];
    const float* wq_pw  = (const float*)d_in[2];
    const float* bq     = (const float*)d_in[3];
    const float* wk_dw  = (const float*)d_in[4];
    const float* wk_pw  = (const float*)d_in[5];
    const float* bk     = (const float*)d_in[6];
    const float* wv_dw  = (const float*)d_in[7];
    const float* wv_pw  = (const float*)d_in[8];
    const float* bv     = (const float*)d_in[9];
    const float* proj_w = (const float*)d_in[10];
    const float* proj_b = (const float*)d_in[11];
    float* out = (float*)d_out;

    // workspace (~47.3 MB):
    //   qkf   : 2*QC fp32 [p][c]
    //   vh    : QC bf16 [4][QTOT][32]
    //   qk_hi : 2*QC bf16, qk_lo : 2*QC bf16
    //   v_bf  : QC bf16 (aliased as att_bf after qkv_mfma consumes it)
    //   wbuf  : WB_TOT bf16 prepped pointwise/proj weights
    float* qkf = (float*)d_ws;
    unsigned short* vh = (unsigned short*)(qkf + (size_t)2 * QC);
    unsigned short* qk_hi = vh + (size_t)QC;
    unsigned short* qk_lo = qk_hi + (size_t)2 * QC;
    unsigned short* v_bf = qk_lo + (size_t)2 * QC;
    unsigned short* wbuf = v_bf + (size_t)QC;
    unsigned short* att_bf = v_bf;

    dwcvt_kernel<<<dim3(289, 4), 256, 0, stream>>>(
        vid, wq_dw, wk_dw, wv_dw, wq_pw, wk_pw, wv_pw, proj_w,
        qk_hi, qk_lo, v_bf, wbuf);
    qkv_mfma<<<dim3(QTOT / 64, 3), 256, 0, stream>>>(
        qk_hi, qk_lo, v_bf, wbuf, bq, bk, bv, qkf, vh);
    attn_kernel<<<dim3(TT * HH * (WW / SEG), 4), 1024, 0, stream>>>(
        qkf, qkf + (size_t)QC, vh, att_bf);
    proj_mfma<<<QTOT / 64, 256, 0, stream>>>(att_bf, wbuf, proj_b, out);
}

// Round 10
// 167.116 us; speedup vs baseline: 1.1632x; 1.0795x over previous
//
#include <hip/hip_runtime.h>
#include <math.h>

#define TT 2
#define CH 128
#define HH 96
#define WW 96
#define HWS 9216            // H*W
#define QTOT 18432          // T*H*W
#define QC (QTOT*CH)
#define HD 32
#define KTOP 16
#define SCALE 0.17677669529663687f  // 32^-0.5

#define SEG 16              // queries per attn block (one row segment)
#define PR 8                // patch rows
#define PC 23               // patch cols
#define PSTRIDE 36          // floats per patch pixel in LDS (144 B)

#define FPX 32              // pixels per fused dw+qkv block

typedef __attribute__((ext_vector_type(8))) short short8;
typedef __attribute__((ext_vector_type(4))) float floatx4;

__device__ __forceinline__ unsigned short f2bf(float f) {
    union { float f; unsigned u; } x; x.f = f;
    unsigned r = x.u + 0x7fffu + ((x.u >> 16) & 1u);
    return (unsigned short)(r >> 16);
}
__device__ __forceinline__ float bf2f(unsigned short h) {
    return __uint_as_float(((unsigned)h) << 16);
}

__device__ __forceinline__ int refl(int x, int n) {
    x = x < 0 ? -x : x;
    return x >= n ? 2 * (n - 1) - x : x;
}

// pack 8 fp32 -> 8 bf16 (hi) ; identical values to the old wbuf prep
__device__ __forceinline__ short8 pack_hi(float4 a, float4 b) {
    union { unsigned short us[8]; short8 v; } u;
    u.us[0] = f2bf(a.x); u.us[1] = f2bf(a.y);
    u.us[2] = f2bf(a.z); u.us[3] = f2bf(a.w);
    u.us[4] = f2bf(b.x); u.us[5] = f2bf(b.y);
    u.us[6] = f2bf(b.z); u.us[7] = f2bf(b.w);
    return u.v;
}
__device__ __forceinline__ short8 pack_lo(float4 a, float4 b, short8 hi) {
    union { unsigned short us[8]; short8 v; } u;
    u.us[0] = f2bf(a.x - bf2f((unsigned short)hi[0]));
    u.us[1] = f2bf(a.y - bf2f((unsigned short)hi[1]));
    u.us[2] = f2bf(a.z - bf2f((unsigned short)hi[2]));
    u.us[3] = f2bf(a.w - bf2f((unsigned short)hi[3]));
    u.us[4] = f2bf(b.x - bf2f((unsigned short)hi[4]));
    u.us[5] = f2bf(b.y - bf2f((unsigned short)hi[5]));
    u.us[6] = f2bf(b.z - bf2f((unsigned short)hi[6]));
    u.us[7] = f2bf(b.w - bf2f((unsigned short)hi[7]));
    return u.v;
}

// ------ FUSED depthwise 3x3 + bf16 split + qkv GEMMs (one dispatch, no wbuf) --------
// 576 blocks x 512 thr; block = 32 px x 128 ch. Phase 1: branch-free dw (clamp
// index, multiply exact 0/1 mask -- adds +0.0 in-sequence, bit-identical to the
// old skip version) with dw taps staged in LDS; hi/lo bf16 packed into 5 LDS
// planes [32][136] (pad -> 2-way banks). Phase 2: q GEMM (waves 0-3), k GEMM
// (waves 4-7), v GEMM (pt split by wave half); B converted on the fly from fp32
// weights with the same f2bf as the old wbuf prep (bit-identical values, same
// kc order, same 3-MFMA hi/lo sequence). Kills the 47 MB intermediate HBM
// round-trip and one dispatch.
__global__ __launch_bounds__(512) void dwqkv_kernel(
    const float* __restrict__ x,
    const float* __restrict__ wqd, const float* __restrict__ wkd, const float* __restrict__ wvd,
    const float* __restrict__ wq_pw, const float* __restrict__ wk_pw, const float* __restrict__ wv_pw,
    const float* __restrict__ bq, const float* __restrict__ bk, const float* __restrict__ bv,
    float* __restrict__ qkf,            // q -> qkf[0], k -> qkf[1] ([p][c] fp32)
    unsigned short* __restrict__ vh)    // [4][QTOT][32] bf16
{
    __shared__ float wS[3456];                    // 13.8 KB: wq|wk|wv dw taps (128x9 each)
    __shared__ unsigned short pl[5][FPX * 136];   // 43.5 KB: q_hi,q_lo,k_hi,k_lo,v
    int t = threadIdx.x;
    for (int r = t; r < 1152; r += 512) {
        wS[r] = wqd[r]; wS[1152 + r] = wkd[r]; wS[2304 + r] = wvd[r];
    }
    int p0 = blockIdx.x * FPX;
    int tt0 = p0 / HWS;
    int hw0 = p0 - tt0 * HWS;
    int i0 = hw0 / WW, j0 = hw0 - i0 * WW;        // block-uniform (32 | 96)
    int px = t & 31, cgp = t >> 5;                // cgp in [0,16)
    int c0 = cgp * 8;
    int j = j0 + px;

    int off[9]; float mk[9];
#pragma unroll
    for (int r = 0; r < 3; r++) {
        int ii = i0 + r - 1;
        float rm = (ii >= 0 && ii < HH) ? 1.f : 0.f;
        int iic = ii < 0 ? 0 : (ii >= HH ? HH - 1 : ii);
#pragma unroll
        for (int s = 0; s < 3; s++) {
            int jj = j + s - 1;
            float cm = (jj >= 0 && jj < WW) ? 1.f : 0.f;
            int jjc = jj < 0 ? 0 : (jj >= WW ? WW - 1 : jj);
            off[r * 3 + s] = iic * WW + jjc;
            mk[r * 3 + s] = rm * cm;
        }
    }
    __syncthreads();   // weights staged

    unsigned qh[4], ql2[4], kh[4], kl[4], vh4[4];
#pragma unroll
    for (int ic = 0; ic < 8; ic += 2) {
        float sv[3][2];
#pragma unroll
        for (int u = 0; u < 2; u++) {
            int c = c0 + ic + u;
            const float* xp = x + (size_t)(tt0 * CH + c) * HWS;
            const float* w0 = &wS[c * 9];
            const float* w1 = &wS[1152 + c * 9];
            const float* w2 = &wS[2304 + c * 9];
            float s0 = 0.f, s1 = 0.f, s2 = 0.f;
#pragma unroll
            for (int q9 = 0; q9 < 9; q9++) {
                float xv = xp[off[q9]] * mk[q9];   // mask=1 -> exact; mask=0 -> +0.0
                s0 += xv * w0[q9]; s1 += xv * w1[q9]; s2 += xv * w2[q9];
            }
            sv[0][u] = s0; sv[1][u] = s1; sv[2][u] = s2;
        }
        int w = ic >> 1;
        unsigned short h0 = f2bf(sv[0][0]), h1 = f2bf(sv[0][1]);
        qh[w] = h0 | ((unsigned)h1 << 16);
        ql2[w] = f2bf(sv[0][0] - bf2f(h0)) | ((unsigned)f2bf(sv[0][1] - bf2f(h1)) << 16);
        h0 = f2bf(sv[1][0]); h1 = f2bf(sv[1][1]);
        kh[w] = h0 | ((unsigned)h1 << 16);
        kl[w] = f2bf(sv[1][0] - bf2f(h0)) | ((unsigned)f2bf(sv[1][1] - bf2f(h1)) << 16);
        vh4[w] = f2bf(sv[2][0]) | ((unsigned)f2bf(sv[2][1]) << 16);
    }
    int lb = px * 136 + c0;
    uint4 pk;
    pk.x = qh[0];  pk.y = qh[1];  pk.z = qh[2];  pk.w = qh[3];  *(uint4*)&pl[0][lb] = pk;
    pk.x = ql2[0]; pk.y = ql2[1]; pk.z = ql2[2]; pk.w = ql2[3]; *(uint4*)&pl[1][lb] = pk;
    pk.x = kh[0];  pk.y = kh[1];  pk.z = kh[2];  pk.w = kh[3];  *(uint4*)&pl[2][lb] = pk;
    pk.x = kl[0];  pk.y = kl[1];  pk.z = kl[2];  pk.w = kl[3];  *(uint4*)&pl[3][lb] = pk;
    pk.x = vh4[0]; pk.y = vh4[1]; pk.z = vh4[2]; pk.w = vh4[3]; *(uint4*)&pl[4][lb] = pk;
    __syncthreads();

    // ---- phase 2: GEMMs. waves 0-3: q, waves 4-7: k (o0 = (wv&3)*32)
    int wv = t >> 6, lane = t & 63;
    int m = lane & 15, quad = lane >> 4;
    int o0 = (wv & 3) * 32;
    bool isQ = wv < 4;
    const float* Wf = isQ ? wq_pw : wk_pw;
    const unsigned short* Ah = pl[isQ ? 0 : 2];
    const unsigned short* Al = pl[isQ ? 1 : 3];
    const float* bias = isQ ? bq : bk;
    float scale = isQ ? SCALE : 1.f;
    float* O = qkf + (isQ ? 0 : (size_t)QC);
    float bb[2];
#pragma unroll
    for (int ot = 0; ot < 2; ot++) bb[ot] = bias[o0 + ot * 16 + m];
    floatx4 acc[2][2];
#pragma unroll
    for (int i = 0; i < 2; i++)
#pragma unroll
        for (int jj2 = 0; jj2 < 2; jj2++) acc[i][jj2] = (floatx4){0.f, 0.f, 0.f, 0.f};
#pragma unroll
    for (int kc = 0; kc < 4; kc++) {
        short8 avh[2], avl[2], bh2[2], bl2[2];
#pragma unroll
        for (int pt = 0; pt < 2; pt++) {
            int lidx = (pt * 16 + m) * 136 + kc * 32 + quad * 8;
            avh[pt] = *(const short8*)&Ah[lidx];
            avl[pt] = *(const short8*)&Al[lidx];
        }
#pragma unroll
        for (int ot = 0; ot < 2; ot++) {
            const float* wrow = Wf + (size_t)(o0 + ot * 16 + m) * CH + kc * 32 + quad * 8;
            float4 wa = *(const float4*)wrow;
            float4 wb = *(const float4*)(wrow + 4);
            bh2[ot] = pack_hi(wa, wb);
            bl2[ot] = pack_lo(wa, wb, bh2[ot]);
        }
#pragma unroll
        for (int pt = 0; pt < 2; pt++)
#pragma unroll
            for (int ot = 0; ot < 2; ot++) {
                acc[pt][ot] = __builtin_amdgcn_mfma_f32_16x16x32_bf16(avh[pt], bh2[ot], acc[pt][ot], 0, 0, 0);
                acc[pt][ot] = __builtin_amdgcn_mfma_f32_16x16x32_bf16(avh[pt], bl2[ot], acc[pt][ot], 0, 0, 0);
                acc[pt][ot] = __builtin_amdgcn_mfma_f32_16x16x32_bf16(avl[pt], bh2[ot], acc[pt][ot], 0, 0, 0);
            }
    }
#pragma unroll
    for (int pt = 0; pt < 2; pt++)
#pragma unroll
        for (int ot = 0; ot < 2; ot++)
#pragma unroll
            for (int reg = 0; reg < 4; reg++) {
                int p = p0 + pt * 16 + quad * 4 + reg;
                O[(size_t)p * CH + o0 + ot * 16 + m] = (acc[pt][ot][reg] + bb[ot]) * scale;
            }

    // ---- v GEMM: pt split by wave half (wv>>2), same per-element math as before
    int ptv = wv >> 2;
    float bbv[2];
#pragma unroll
    for (int ot = 0; ot < 2; ot++) bbv[ot] = bv[o0 + ot * 16 + m];
    floatx4 accv[2];
    accv[0] = (floatx4){0.f, 0.f, 0.f, 0.f};
    accv[1] = (floatx4){0.f, 0.f, 0.f, 0.f};
#pragma unroll
    for (int kc = 0; kc < 4; kc++) {
        int lidx = (ptv * 16 + m) * 136 + kc * 32 + quad * 8;
        short8 av = *(const short8*)&pl[4][lidx];
#pragma unroll
        for (int ot = 0; ot < 2; ot++) {
            const float* wrow = wv_pw + (size_t)(o0 + ot * 16 + m) * CH + kc * 32 + quad * 8;
            short8 bhv = pack_hi(*(const float4*)wrow, *(const float4*)(wrow + 4));
            accv[ot] = __builtin_amdgcn_mfma_f32_16x16x32_bf16(av, bhv, accv[ot], 0, 0, 0);
        }
    }
    unsigned short* vhh = vh + (size_t)(wv & 3) * QTOT * 32;
#pragma unroll
    for (int ot = 0; ot < 2; ot++)
#pragma unroll
        for (int reg = 0; reg < 4; reg++) {
            int p = p0 + ptv * 16 + quad * 4 + reg;
            vhh[(size_t)p * 32 + ot * 16 + m] = f2bf(accv[ot][reg] + bbv[ot]);
        }
}

// ------ attention (unchanged from r9 best-known: two-level ballot select) -----------
__global__ __launch_bounds__(1024) void attn_kernel(
    const float* __restrict__ q,    // qkf[0] [p][128] fp32
    const float* __restrict__ k,    // qkf[1]
    const unsigned short* __restrict__ vh,   // [4][QTOT][32] bf16
    unsigned short* __restrict__ att)        // [p][128] bf16
{
    __shared__ float kp[PR * PC * PSTRIDE];   // 25.9 KB
    __shared__ uint2 slot[16][KTOP];          // per-wave compaction, 2 KB
    int h = blockIdx.y;
    int n = blockIdx.x;
    int seg = (n & 7) * 144 + (n >> 3);       // XCD-band swizzle
    int qj0 = (seg % (WW / SEG)) * SEG;
    int qi = (seg / (WW / SEG)) % HH;
    int tt = seg / ((WW / SEG) * HH);
    int t = threadIdx.x;

#pragma unroll
    for (int r = 0; r < 2; r++) {
        int f = r * 1024 + t;
        if (f < PR * PC * 8) {
            int pix = f >> 3, d4 = f & 7;
            int ci = pix / PC, cj = pix - ci * PC;
            int gi = refl(qi + ci - 4, HH);
            int gj = refl(qj0 + cj - 4, WW);
            int gp = tt * HWS + gi * WW + gj;
            *(float4*)(&kp[pix * PSTRIDE + d4 * 4]) =
                *(const float4*)(k + (size_t)gp * CH + h * HD + d4 * 4);
        }
    }

    int wv = t >> 6, lane = t & 63;
    int wvu = __builtin_amdgcn_readfirstlane(wv);
    if (lane < KTOP) slot[wvu][lane] = make_uint2(0u, 0u);
    __syncthreads();

    int ci = lane >> 3, cjo = lane & 7;
    int di = ci - 4, dj = cjo - 4;
    int rowoff = tt * HWS + refl(qi + di, HH) * WW;
    const unsigned long long below = (1ull << lane) - 1ull;
    const unsigned short* vhh = vh + (size_t)h * QTOT * 32;

    int ql = wvu;
    int qj = qj0 + ql;
    int p = tt * HWS + qi * WW + qj;

    const float* qp = q + (size_t)p * CH + h * HD;
    int pixq = ci * PC + ql + cjo;
    const float* kr = &kp[pixq * PSTRIDE];
    float dist = 0.f;
#pragma unroll
    for (int dd = 0; dd < 8; dd++) {
        float4 qv = *(const float4*)(qp + dd * 4);
        float4 kv = *(const float4*)(kr + dd * 4);
        dist += qv.x * kv.x + qv.y * kv.y + qv.z * kv.z + qv.w * kv.w;
    }

    unsigned u = __float_as_uint(dist);
    unsigned key = (u & 0x80000000u) ? ~u : (u | 0x80000000u);
    unsigned khi = key >> 16, klo = key & 0xffffu;
    float e = __expf(dist);

    unsigned Lh = 0u;
#pragma unroll
    for (int bit = 15; bit >= 0; --bit) {
        unsigned C = Lh | (1u << bit);
        unsigned long long b = __ballot(khi >= C);
        Lh = (__popcll(b) >= KTOP) ? C : Lh;
    }
    bool gth = khi > Lh;
    bool eqh = (khi == Lh);
    unsigned long long gtmh = __ballot(gth);
    unsigned long long eqmh = __ballot(eqh);
    int need = KTOP - __popcll(gtmh);
    bool selb;
    unsigned long long selm;
    if (__popcll(eqmh) == need) {
        selb = gth || eqh;
        selm = gtmh | eqmh;
    } else {
        unsigned Ll = 0u;
#pragma unroll
        for (int bit = 15; bit >= 0; --bit) {
            unsigned C = Ll | (1u << bit);
            unsigned long long b = __ballot(klo >= C) & eqmh;
            Ll = (__popcll(b) >= need) ? C : Ll;
        }
        unsigned long long gtml = __ballot(klo > Ll) & eqmh;
        unsigned long long eqml = __ballot(klo == Ll) & eqmh;
        int needl = need - __popcll(gtml);
        int rk = __popcll(eqml & below);
        bool gtl = eqh && (klo > Ll);
        bool eql = eqh && (klo == Ll);
        selb = gth || gtl || (eql && rk < needl);
        selm = __ballot(selb);
    }
    int rksel = __builtin_amdgcn_mbcnt_hi(
        (unsigned)(selm >> 32), __builtin_amdgcn_mbcnt_lo((unsigned)selm, 0));
    int cpix = rowoff + refl(qj + dj, WW);
    if (selb && rksel < KTOP)
        slot[wvu][rksel] = make_uint2(__float_as_uint(e), (unsigned)(cpix << 5));

    const int d = lane & (HD - 1);
    const int half8 = (lane >> 5) * 8;
    float acc = 0.f, denom = 0.f;
#pragma unroll
    for (int r = 0; r < 8; r++) {
        uint2 sp = slot[wvu][half8 + r];
        float a0 = __uint_as_float(sp.x);
        denom += a0;
        acc += a0 * bf2f(vhh[(size_t)sp.y + d]);
    }
    acc += __shfl_xor(acc, 32);
    denom += __shfl_xor(denom, 32);
    if (lane < HD)
        att[(size_t)p * CH + h * HD + lane] =
            f2bf(acc * __builtin_amdgcn_rcpf(denom));
}

// ------ proj via bf16 MFMA: B converted on the fly from fp32 proj_w (same f2bf) -----
__global__ __launch_bounds__(256) void proj_mfma(
    const unsigned short* __restrict__ A,   // att_bf [p][c] bf16
    const float* __restrict__ proj_w,
    const float* __restrict__ bias,
    float* __restrict__ out)                // NCHW fp32
{
    int t = threadIdx.x;
    int wv = t >> 6, lane = t & 63;
    int m = lane & 15, quad = lane >> 4;
    int p0 = blockIdx.x * 64;
    int o0 = wv * 32;
    float bb[2][4];
#pragma unroll
    for (int ot = 0; ot < 2; ot++)
#pragma unroll
        for (int reg = 0; reg < 4; reg++) bb[ot][reg] = bias[o0 + ot * 16 + quad * 4 + reg];
    floatx4 acc[2][4];
#pragma unroll
    for (int i = 0; i < 2; i++)
#pragma unroll
        for (int jj2 = 0; jj2 < 4; jj2++) acc[i][jj2] = (floatx4){0.f, 0.f, 0.f, 0.f};
#pragma unroll
    for (int kc = 0; kc < 4; kc++) {
        short8 a[2], b[4];
#pragma unroll
        for (int ot = 0; ot < 2; ot++) {
            const float* wrow = proj_w + (size_t)(o0 + ot * 16 + m) * CH + kc * 32 + quad * 8;
            a[ot] = pack_hi(*(const float4*)wrow, *(const float4*)(wrow + 4));
        }
#pragma unroll
        for (int pt = 0; pt < 4; pt++)
            b[pt] = *(const short8*)(A + (size_t)(p0 + pt * 16 + m) * CH + kc * 32 + quad * 8);
#pragma unroll
        for (int ot = 0; ot < 2; ot++)
#pragma unroll
            for (int pt = 0; pt < 4; pt++)
                acc[ot][pt] = __builtin_amdgcn_mfma_f32_16x16x32_bf16(a[ot], b[pt], acc[ot][pt], 0, 0, 0);
    }
    int tt = p0 / HWS;
    int hwb = p0 - tt * HWS;
#pragma unroll
    for (int ot = 0; ot < 2; ot++)
#pragma unroll
        for (int pt = 0; pt < 4; pt++)
#pragma unroll
            for (int reg = 0; reg < 4; reg++) {
                int o = o0 + ot * 16 + quad * 4 + reg;
                int hw = hwb + pt * 16 + m;
                out[((size_t)(tt * CH + o)) * HWS + hw] = acc[ot][pt][reg] + bb[ot][reg];
            }
}

extern "C" void kernel_launch(void* const* d_in, const int* in_sizes, int n_in,
                              void* d_out, int out_size, void* d_ws, size_t ws_size,
                              hipStream_t stream) {
    const float* vid    = (const float*)d_in[0];
    const float* wq_dw  = (const float*)d_in[1];
    const float* wq_pw  = (const float*)d_in[2];
    const float* bq     = (const float*)d_in[3];
    const float* wk_dw  = (const float*)d_in[4];
    const float* wk_pw  = (const float*)d_in[5];
    const float* bk     = (const float*)d_in[6];
    const float* wv_dw  = (const float*)d_in[7];
    const float* wv_pw  = (const float*)d_in[8];
    const float* bv     = (const float*)d_in[9];
    const float* proj_w = (const float*)d_in[10];
    const float* proj_b = (const float*)d_in[11];
    float* out = (float*)d_out;

    // workspace (~28.3 MB): qkf 2*QC fp32 | vh QC bf16 | att_bf QC bf16
    float* qkf = (float*)d_ws;
    unsigned short* vh = (unsigned short*)(qkf + (size_t)2 * QC);
    unsigned short* att_bf = vh + (size_t)QC;

    dwqkv_kernel<<<QTOT / FPX, 512, 0, stream>>>(
        vid, wq_dw, wk_dw, wv_dw, wq_pw, wk_pw, wv_pw, bq, bk, bv, qkf, vh);
    attn_kernel<<<dim3(TT * HH * (WW / SEG), 4), 1024, 0, stream>>>(
        qkf, qkf + (size_t)QC, vh, att_bf);
    proj_mfma<<<QTOT / 64, 256, 0, stream>>>(att_bf, proj_w, proj_b, out);
}

// Round 11
// 166.994 us; speedup vs baseline: 1.1641x; 1.0007x over previous
//
#include <hip/hip_runtime.h>
#include <math.h>

#define TT 2
#define CH 128
#define HH 96
#define WW 96
#define HWS 9216            // H*W
#define QTOT 18432          // T*H*W
#define QC (QTOT*CH)
#define HD 32
#define KTOP 16
#define SCALE 0.17677669529663687f  // 32^-0.5

#define SEG 16              // queries per attn block (one row segment)
#define PR 8                // patch rows
#define PC 23               // patch cols
#define PSTRIDE 36          // floats per patch pixel in LDS (144 B)

#define FPX 32              // pixels per fused dw+qkv block

// wbuf (bf16 shorts): wq_hi@0 wq_lo@16384 wk_hi@32768 wk_lo@49152 wv_hi@65536 pj_hi@81920
#define WB_TOT 98304

typedef __attribute__((ext_vector_type(8))) short short8;
typedef __attribute__((ext_vector_type(4))) float floatx4;

__device__ __forceinline__ unsigned short f2bf(float f) {
    union { float f; unsigned u; } x; x.f = f;
    unsigned r = x.u + 0x7fffu + ((x.u >> 16) & 1u);
    return (unsigned short)(r >> 16);
}
__device__ __forceinline__ float bf2f(unsigned short h) {
    return __uint_as_float(((unsigned)h) << 16);
}

__device__ __forceinline__ int refl(int x, int n) {
    x = x < 0 ? -x : x;
    return x >= n ? 2 * (n - 1) - x : x;
}

// ------ one-shot pointwise/proj weight conversion (4 blocks; runs BEFORE dwqkv).
// r10 did this per-block (576x redundant, ~900 VALU inst/thread); restoring the
// one-shot prep removes that redundancy. Same f2bf math -> bit-identical values.
__global__ __launch_bounds__(256) void wprep_kernel(
    const float* __restrict__ wq_pw, const float* __restrict__ wk_pw,
    const float* __restrict__ wv_pw, const float* __restrict__ proj_w,
    unsigned short* __restrict__ wbuf)
{
    int t = threadIdx.x;
    int y = blockIdx.x;               // 0=wq_pw(hi+lo) 1=wk_pw(hi+lo) 2=wv_pw 3=proj_w
    const float* src = y == 0 ? wq_pw : (y == 1 ? wk_pw : (y == 2 ? wv_pw : proj_w));
    unsigned short* hi = wbuf + (y == 0 ? 0 : (y == 1 ? 32768 : (y == 2 ? 65536 : 81920)));
#pragma unroll
    for (int r = 0; r < 16; r++) {
        int idx = r * 256 + t;        // float4 index, 4096 total = 128x128
        float4 w4 = *(const float4*)(src + idx * 4);
        unsigned short hx = f2bf(w4.x), hy = f2bf(w4.y), hz = f2bf(w4.z), hw = f2bf(w4.w);
        uint2 pk;
        pk.x = hx | ((unsigned)hy << 16); pk.y = hz | ((unsigned)hw << 16);
        *(uint2*)(hi + idx * 4) = pk;
        if (y < 2) {
            unsigned short lx = f2bf(w4.x - bf2f(hx)), ly = f2bf(w4.y - bf2f(hy));
            unsigned short lz = f2bf(w4.z - bf2f(hz)), lw = f2bf(w4.w - bf2f(hw));
            pk.x = lx | ((unsigned)ly << 16); pk.y = lz | ((unsigned)lw << 16);
            *(uint2*)(hi + 16384 + idx * 4) = pk;
        }
    }
}

// ------ FUSED depthwise 3x3 + bf16 split + qkv GEMMs (no intermediate HBM trip) -----
// 576 blocks x 512 thr; block = 32 px x 128 ch. Phase 1: branch-free dw with taps
// in LDS; hi/lo bf16 packed into 5 LDS planes [32][136]. Phase 2: q GEMM (waves
// 0-3), k GEMM (waves 4-7), v GEMM (pt split by wave half); B fragments read
// directly from the PREPPED bf16 weights in global (L2-resident, r7-proven
// pattern) -- identical values/order to r10's on-the-fly conversion.
__global__ __launch_bounds__(512) void dwqkv_kernel(
    const float* __restrict__ x,
    const float* __restrict__ wqd, const float* __restrict__ wkd, const float* __restrict__ wvd,
    const unsigned short* __restrict__ wbuf,
    const float* __restrict__ bq, const float* __restrict__ bk, const float* __restrict__ bv,
    float* __restrict__ qkf,            // q -> qkf[0], k -> qkf[1] ([p][c] fp32)
    unsigned short* __restrict__ vh)    // [4][QTOT][32] bf16
{
    __shared__ float wS[3456];                    // 13.8 KB: wq|wk|wv dw taps (128x9 each)
    __shared__ unsigned short pl[5][FPX * 136];   // 43.5 KB: q_hi,q_lo,k_hi,k_lo,v
    int t = threadIdx.x;
    for (int r = t; r < 1152; r += 512) {
        wS[r] = wqd[r]; wS[1152 + r] = wkd[r]; wS[2304 + r] = wvd[r];
    }
    int p0 = blockIdx.x * FPX;
    int tt0 = p0 / HWS;
    int hw0 = p0 - tt0 * HWS;
    int i0 = hw0 / WW, j0 = hw0 - i0 * WW;        // block-uniform (32 | 96)
    int px = t & 31, cgp = t >> 5;                // cgp in [0,16)
    int c0 = cgp * 8;
    int j = j0 + px;

    int off[9]; float mk[9];
#pragma unroll
    for (int r = 0; r < 3; r++) {
        int ii = i0 + r - 1;
        float rm = (ii >= 0 && ii < HH) ? 1.f : 0.f;
        int iic = ii < 0 ? 0 : (ii >= HH ? HH - 1 : ii);
#pragma unroll
        for (int s = 0; s < 3; s++) {
            int jj = j + s - 1;
            float cm = (jj >= 0 && jj < WW) ? 1.f : 0.f;
            int jjc = jj < 0 ? 0 : (jj >= WW ? WW - 1 : jj);
            off[r * 3 + s] = iic * WW + jjc;
            mk[r * 3 + s] = rm * cm;
        }
    }
    __syncthreads();   // weights staged

    unsigned qh[4], ql2[4], kh[4], kl[4], vh4[4];
#pragma unroll
    for (int ic = 0; ic < 8; ic += 2) {
        float sv[3][2];
#pragma unroll
        for (int u = 0; u < 2; u++) {
            int c = c0 + ic + u;
            const float* xp = x + (size_t)(tt0 * CH + c) * HWS;
            const float* w0 = &wS[c * 9];
            const float* w1 = &wS[1152 + c * 9];
            const float* w2 = &wS[2304 + c * 9];
            float s0 = 0.f, s1 = 0.f, s2 = 0.f;
#pragma unroll
            for (int q9 = 0; q9 < 9; q9++) {
                float xv = xp[off[q9]] * mk[q9];   // mask=1 -> exact; mask=0 -> +0.0
                s0 += xv * w0[q9]; s1 += xv * w1[q9]; s2 += xv * w2[q9];
            }
            sv[0][u] = s0; sv[1][u] = s1; sv[2][u] = s2;
        }
        int w = ic >> 1;
        unsigned short h0 = f2bf(sv[0][0]), h1 = f2bf(sv[0][1]);
        qh[w] = h0 | ((unsigned)h1 << 16);
        ql2[w] = f2bf(sv[0][0] - bf2f(h0)) | ((unsigned)f2bf(sv[0][1] - bf2f(h1)) << 16);
        h0 = f2bf(sv[1][0]); h1 = f2bf(sv[1][1]);
        kh[w] = h0 | ((unsigned)h1 << 16);
        kl[w] = f2bf(sv[1][0] - bf2f(h0)) | ((unsigned)f2bf(sv[1][1] - bf2f(h1)) << 16);
        vh4[w] = f2bf(sv[2][0]) | ((unsigned)f2bf(sv[2][1]) << 16);
    }
    int lb = px * 136 + c0;
    uint4 pk;
    pk.x = qh[0];  pk.y = qh[1];  pk.z = qh[2];  pk.w = qh[3];  *(uint4*)&pl[0][lb] = pk;
    pk.x = ql2[0]; pk.y = ql2[1]; pk.z = ql2[2]; pk.w = ql2[3]; *(uint4*)&pl[1][lb] = pk;
    pk.x = kh[0];  pk.y = kh[1];  pk.z = kh[2];  pk.w = kh[3];  *(uint4*)&pl[2][lb] = pk;
    pk.x = kl[0];  pk.y = kl[1];  pk.z = kl[2];  pk.w = kl[3];  *(uint4*)&pl[3][lb] = pk;
    pk.x = vh4[0]; pk.y = vh4[1]; pk.z = vh4[2]; pk.w = vh4[3]; *(uint4*)&pl[4][lb] = pk;
    __syncthreads();

    // ---- phase 2: GEMMs. waves 0-3: q, waves 4-7: k (o0 = (wv&3)*32)
    int wv = t >> 6, lane = t & 63;
    int m = lane & 15, quad = lane >> 4;
    int o0 = (wv & 3) * 32;
    bool isQ = wv < 4;
    const unsigned short* Wh_g = wbuf + (isQ ? 0 : 32768);
    const unsigned short* Wl_g = Wh_g + 16384;
    const unsigned short* Ah = pl[isQ ? 0 : 2];
    const unsigned short* Al = pl[isQ ? 1 : 3];
    const float* bias = isQ ? bq : bk;
    float scale = isQ ? SCALE : 1.f;
    float* O = qkf + (isQ ? 0 : (size_t)QC);
    float bb[2];
#pragma unroll
    for (int ot = 0; ot < 2; ot++) bb[ot] = bias[o0 + ot * 16 + m];
    floatx4 acc[2][2];
#pragma unroll
    for (int i = 0; i < 2; i++)
#pragma unroll
        for (int jj2 = 0; jj2 < 2; jj2++) acc[i][jj2] = (floatx4){0.f, 0.f, 0.f, 0.f};
#pragma unroll
    for (int kc = 0; kc < 4; kc++) {
        short8 avh[2], avl[2], bh2[2], bl2[2];
#pragma unroll
        for (int pt = 0; pt < 2; pt++) {
            int lidx = (pt * 16 + m) * 136 + kc * 32 + quad * 8;
            avh[pt] = *(const short8*)&Ah[lidx];
            avl[pt] = *(const short8*)&Al[lidx];
        }
#pragma unroll
        for (int ot = 0; ot < 2; ot++) {
            size_t widx = (size_t)(o0 + ot * 16 + m) * CH + kc * 32 + quad * 8;
            bh2[ot] = *(const short8*)(Wh_g + widx);
            bl2[ot] = *(const short8*)(Wl_g + widx);
        }
#pragma unroll
        for (int pt = 0; pt < 2; pt++)
#pragma unroll
            for (int ot = 0; ot < 2; ot++) {
                acc[pt][ot] = __builtin_amdgcn_mfma_f32_16x16x32_bf16(avh[pt], bh2[ot], acc[pt][ot], 0, 0, 0);
                acc[pt][ot] = __builtin_amdgcn_mfma_f32_16x16x32_bf16(avh[pt], bl2[ot], acc[pt][ot], 0, 0, 0);
                acc[pt][ot] = __builtin_amdgcn_mfma_f32_16x16x32_bf16(avl[pt], bh2[ot], acc[pt][ot], 0, 0, 0);
            }
    }
#pragma unroll
    for (int pt = 0; pt < 2; pt++)
#pragma unroll
        for (int ot = 0; ot < 2; ot++)
#pragma unroll
            for (int reg = 0; reg < 4; reg++) {
                int p = p0 + pt * 16 + quad * 4 + reg;
                O[(size_t)p * CH + o0 + ot * 16 + m] = (acc[pt][ot][reg] + bb[ot]) * scale;
            }

    // ---- v GEMM: pt split by wave half (wv>>2), prepped wv_hi weights
    const unsigned short* Wv_g = wbuf + 65536;
    int ptv = wv >> 2;
    float bbv[2];
#pragma unroll
    for (int ot = 0; ot < 2; ot++) bbv[ot] = bv[o0 + ot * 16 + m];
    floatx4 accv[2];
    accv[0] = (floatx4){0.f, 0.f, 0.f, 0.f};
    accv[1] = (floatx4){0.f, 0.f, 0.f, 0.f};
#pragma unroll
    for (int kc = 0; kc < 4; kc++) {
        int lidx = (ptv * 16 + m) * 136 + kc * 32 + quad * 8;
        short8 av = *(const short8*)&pl[4][lidx];
#pragma unroll
        for (int ot = 0; ot < 2; ot++) {
            size_t widx = (size_t)(o0 + ot * 16 + m) * CH + kc * 32 + quad * 8;
            short8 bhv = *(const short8*)(Wv_g + widx);
            accv[ot] = __builtin_amdgcn_mfma_f32_16x16x32_bf16(av, bhv, accv[ot], 0, 0, 0);
        }
    }
    unsigned short* vhh = vh + (size_t)(wv & 3) * QTOT * 32;
#pragma unroll
    for (int ot = 0; ot < 2; ot++)
#pragma unroll
        for (int reg = 0; reg < 4; reg++) {
            int p = p0 + ptv * 16 + quad * 4 + reg;
            vhh[(size_t)p * 32 + ot * 16 + m] = f2bf(accv[ot][reg] + bbv[ot]);
        }
}

// ------ attention (unchanged best-known: two-level ballot select) -------------------
__global__ __launch_bounds__(1024) void attn_kernel(
    const float* __restrict__ q,    // qkf[0] [p][128] fp32
    const float* __restrict__ k,    // qkf[1]
    const unsigned short* __restrict__ vh,   // [4][QTOT][32] bf16
    unsigned short* __restrict__ att)        // [p][128] bf16
{
    __shared__ float kp[PR * PC * PSTRIDE];   // 25.9 KB
    __shared__ uint2 slot[16][KTOP];          // per-wave compaction, 2 KB
    int h = blockIdx.y;
    int n = blockIdx.x;
    int seg = (n & 7) * 144 + (n >> 3);       // XCD-band swizzle
    int qj0 = (seg % (WW / SEG)) * SEG;
    int qi = (seg / (WW / SEG)) % HH;
    int tt = seg / ((WW / SEG) * HH);
    int t = threadIdx.x;

#pragma unroll
    for (int r = 0; r < 2; r++) {
        int f = r * 1024 + t;
        if (f < PR * PC * 8) {
            int pix = f >> 3, d4 = f & 7;
            int ci = pix / PC, cj = pix - ci * PC;
            int gi = refl(qi + ci - 4, HH);
            int gj = refl(qj0 + cj - 4, WW);
            int gp = tt * HWS + gi * WW + gj;
            *(float4*)(&kp[pix * PSTRIDE + d4 * 4]) =
                *(const float4*)(k + (size_t)gp * CH + h * HD + d4 * 4);
        }
    }

    int wv = t >> 6, lane = t & 63;
    int wvu = __builtin_amdgcn_readfirstlane(wv);
    if (lane < KTOP) slot[wvu][lane] = make_uint2(0u, 0u);
    __syncthreads();

    int ci = lane >> 3, cjo = lane & 7;
    int di = ci - 4, dj = cjo - 4;
    int rowoff = tt * HWS + refl(qi + di, HH) * WW;
    const unsigned long long below = (1ull << lane) - 1ull;
    const unsigned short* vhh = vh + (size_t)h * QTOT * 32;

    int ql = wvu;
    int qj = qj0 + ql;
    int p = tt * HWS + qi * WW + qj;

    const float* qp = q + (size_t)p * CH + h * HD;
    int pixq = ci * PC + ql + cjo;
    const float* kr = &kp[pixq * PSTRIDE];
    float dist = 0.f;
#pragma unroll
    for (int dd = 0; dd < 8; dd++) {
        float4 qv = *(const float4*)(qp + dd * 4);
        float4 kv = *(const float4*)(kr + dd * 4);
        dist += qv.x * kv.x + qv.y * kv.y + qv.z * kv.z + qv.w * kv.w;
    }

    unsigned u = __float_as_uint(dist);
    unsigned key = (u & 0x80000000u) ? ~u : (u | 0x80000000u);
    unsigned khi = key >> 16, klo = key & 0xffffu;
    float e = __expf(dist);

    unsigned Lh = 0u;
#pragma unroll
    for (int bit = 15; bit >= 0; --bit) {
        unsigned C = Lh | (1u << bit);
        unsigned long long b = __ballot(khi >= C);
        Lh = (__popcll(b) >= KTOP) ? C : Lh;
    }
    bool gth = khi > Lh;
    bool eqh = (khi == Lh);
    unsigned long long gtmh = __ballot(gth);
    unsigned long long eqmh = __ballot(eqh);
    int need = KTOP - __popcll(gtmh);
    bool selb;
    unsigned long long selm;
    if (__popcll(eqmh) == need) {
        selb = gth || eqh;
        selm = gtmh | eqmh;
    } else {
        unsigned Ll = 0u;
#pragma unroll
        for (int bit = 15; bit >= 0; --bit) {
            unsigned C = Ll | (1u << bit);
            unsigned long long b = __ballot(klo >= C) & eqmh;
            Ll = (__popcll(b) >= need) ? C : Ll;
        }
        unsigned long long gtml = __ballot(klo > Ll) & eqmh;
        unsigned long long eqml = __ballot(klo == Ll) & eqmh;
        int needl = need - __popcll(gtml);
        int rk = __popcll(eqml & below);
        bool gtl = eqh && (klo > Ll);
        bool eql = eqh && (klo == Ll);
        selb = gth || gtl || (eql && rk < needl);
        selm = __ballot(selb);
    }
    int rksel = __builtin_amdgcn_mbcnt_hi(
        (unsigned)(selm >> 32), __builtin_amdgcn_mbcnt_lo((unsigned)selm, 0));
    int cpix = rowoff + refl(qj + dj, WW);
    if (selb && rksel < KTOP)
        slot[wvu][rksel] = make_uint2(__float_as_uint(e), (unsigned)(cpix << 5));

    const int d = lane & (HD - 1);
    const int half8 = (lane >> 5) * 8;
    float acc = 0.f, denom = 0.f;
#pragma unroll
    for (int r = 0; r < 8; r++) {
        uint2 sp = slot[wvu][half8 + r];
        float a0 = __uint_as_float(sp.x);
        denom += a0;
        acc += a0 * bf2f(vhh[(size_t)sp.y + d]);
    }
    acc += __shfl_xor(acc, 32);
    denom += __shfl_xor(denom, 32);
    if (lane < HD)
        att[(size_t)p * CH + h * HD + lane] =
            f2bf(acc * __builtin_amdgcn_rcpf(denom));
}

// ------ proj via bf16 MFMA: prepped pj_hi weights direct from L2 --------------------
__global__ __launch_bounds__(256) void proj_mfma(
    const unsigned short* __restrict__ A,   // att_bf [p][c] bf16
    const unsigned short* __restrict__ wbuf,
    const float* __restrict__ bias,
    float* __restrict__ out)                // NCHW fp32
{
    const unsigned short* Wg = wbuf + 81920;
    int t = threadIdx.x;
    int wv = t >> 6, lane = t & 63;
    int m = lane & 15, quad = lane >> 4;
    int p0 = blockIdx.x * 64;
    int o0 = wv * 32;
    float bb[2][4];
#pragma unroll
    for (int ot = 0; ot < 2; ot++)
#pragma unroll
        for (int reg = 0; reg < 4; reg++) bb[ot][reg] = bias[o0 + ot * 16 + quad * 4 + reg];
    floatx4 acc[2][4];
#pragma unroll
    for (int i = 0; i < 2; i++)
#pragma unroll
        for (int jj2 = 0; jj2 < 4; jj2++) acc[i][jj2] = (floatx4){0.f, 0.f, 0.f, 0.f};
#pragma unroll
    for (int kc = 0; kc < 4; kc++) {
        short8 a[2], b[4];
#pragma unroll
        for (int ot = 0; ot < 2; ot++)
            a[ot] = *(const short8*)(Wg + (size_t)(o0 + ot * 16 + m) * CH + kc * 32 + quad * 8);
#pragma unroll
        for (int pt = 0; pt < 4; pt++)
            b[pt] = *(const short8*)(A + (size_t)(p0 + pt * 16 + m) * CH + kc * 32 + quad * 8);
#pragma unroll
        for (int ot = 0; ot < 2; ot++)
#pragma unroll
            for (int pt = 0; pt < 4; pt++)
                acc[ot][pt] = __builtin_amdgcn_mfma_f32_16x16x32_bf16(a[ot], b[pt], acc[ot][pt], 0, 0, 0);
    }
    int tt = p0 / HWS;
    int hwb = p0 - tt * HWS;
#pragma unroll
    for (int ot = 0; ot < 2; ot++)
#pragma unroll
        for (int pt = 0; pt < 4; pt++)
#pragma unroll
            for (int reg = 0; reg < 4; reg++) {
                int o = o0 + ot * 16 + quad * 4 + reg;
                int hw = hwb + pt * 16 + m;
                out[((size_t)(tt * CH + o)) * HWS + hw] = acc[ot][pt][reg] + bb[ot][reg];
            }
}

extern "C" void kernel_launch(void* const* d_in, const int* in_sizes, int n_in,
                              void* d_out, int out_size, void* d_ws, size_t ws_size,
                              hipStream_t stream) {
    const float* vid    = (const float*)d_in[0];
    const float* wq_dw  = (const float*)d_in[1];
    const float* wq_pw  = (const float*)d_in[2];
    const float* bq     = (const float*)d_in[3];
    const float* wk_dw  = (const float*)d_in[4];
    const float* wk_pw  = (const float*)d_in[5];
    const float* bk     = (const float*)d_in[6];
    const float* wv_dw  = (const float*)d_in[7];
    const float* wv_pw  = (const float*)d_in[8];
    const float* bv     = (const float*)d_in[9];
    const float* proj_w = (const float*)d_in[10];
    const float* proj_b = (const float*)d_in[11];
    float* out = (float*)d_out;

    // workspace (~28.5 MB): qkf 2*QC fp32 | vh QC bf16 | att_bf QC bf16 | wbuf
    float* qkf = (float*)d_ws;
    unsigned short* vh = (unsigned short*)(qkf + (size_t)2 * QC);
    unsigned short* att_bf = vh + (size_t)QC;
    unsigned short* wbuf = att_bf + (size_t)QC;

    wprep_kernel<<<4, 256, 0, stream>>>(wq_pw, wk_pw, wv_pw, proj_w, wbuf);
    dwqkv_kernel<<<QTOT / FPX, 512, 0, stream>>>(
        vid, wq_dw, wk_dw, wv_dw, wbuf, bq, bk, bv, qkf, vh);
    attn_kernel<<<dim3(TT * HH * (WW / SEG), 4), 1024, 0, stream>>>(
        qkf, qkf + (size_t)QC, vh, att_bf);
    proj_mfma<<<QTOT / 64, 256, 0, stream>>>(att_bf, wbuf, proj_b, out);
}